// Round 4
// baseline (492.895 us; speedup 1.0000x reference)
//
#include <hip/hip_runtime.h>
#include <hip/hip_bf16.h>
#include <cstdint>

// MoE feed-forward, routed top-2 of 8 experts.
// B=2 S=2048 D=1024 F=2048 E=8 K=2.
// R9: cache-traffic attack. R7/R8 pipelining was null twice -> not drain-bound.
//   Staging traffic at 128x128 tiles = ~768 MB/dispatch (A x16 N-tiles,
//   W x8 M-tiles) = 6.4 TB/s through L2/L3 with every XCD touching all 64 MB
//   of weights (L2 thrash -> L3-BW bound; HBM 13%, MfmaUtil 25% both consistent).
//   (a) 256x128 tiles, 512 thr / 8 waves (2Mx4N, per-wave 128x32), dual-acc
//       128 VGPR -> traffic 768->512 MB (gemm1), 512->384 MB (gemm2).
//   (b) expert = blockIdx.x & 7: round-robin dispatch pins each expert to one
//       XCD -> its 8 MB weight set streams L3->L2 once, M-tile re-reads hit L2.
//   (c) counted-vmcnt pipeline kept (compute phase now ~1100cy, covers latency).
//   (kept: XOR chunk swizzle (0 conflicts), atomic combine, no-atomic routing)

#define Dd 1024
#define Ff 2048
#define Ee 8
#define TOK 4096
#define PAIRS 8192

typedef __attribute__((ext_vector_type(8))) short short8;
typedef __attribute__((ext_vector_type(4))) float floatx4;

__device__ __forceinline__ unsigned short f2bf(float f) {
    unsigned int u = __float_as_uint(f);
    unsigned int r = (u + 0x7FFFu + ((u >> 16) & 1u)) >> 16;
    return (unsigned short)r;
}
__device__ __forceinline__ float bf2f(unsigned short u) {
    return __uint_as_float(((unsigned)u) << 16);
}

// async 16B/lane global->LDS. lds ptr is wave-uniform; lane i lands at lds + i*16B.
__device__ __forceinline__ void gload16(const unsigned short* g, unsigned short* l) {
    __builtin_amdgcn_global_load_lds(
        (const __attribute__((address_space(1))) unsigned int*)g,
        (__attribute__((address_space(3))) unsigned int*)l,
        16, 0, 0);
}

// ---------------- zero out ----------------
__global__ void zero_kernel(float* __restrict__ out, int n4) {
    int i = blockIdx.x * blockDim.x + threadIdx.x;
    if (i < n4) reinterpret_cast<float4*>(out)[i] = make_float4(0.f, 0.f, 0.f, 0.f);
}

// ---------------- gating: fp32 scores, top-2, softmax (NO atomics) ----------------
__global__ void gating_kernel(const float* __restrict__ x, const float* __restrict__ Wg,
                              int* __restrict__ tok_idx, float* __restrict__ tok_prob) {
    int lane = threadIdx.x & 63;
    int w = threadIdx.x >> 6;
    int t = blockIdx.x * 4 + w;

    float xr[16];
    const float* xp = x + (size_t)t * Dd;
#pragma unroll
    for (int i = 0; i < 16; i++) xr[i] = xp[lane + i * 64];

    float sc[Ee];
    for (int e = 0; e < Ee; e++) {
        const float* wp = Wg + (size_t)e * Dd;
        float p = 0.f;
#pragma unroll
        for (int i = 0; i < 16; i++) p += xr[i] * wp[lane + i * 64];
        for (int off = 32; off > 0; off >>= 1) p += __shfl_xor(p, off);
        sc[e] = p;
    }
    if (lane == 0) {
        int e1 = 0, e2 = 0;
        float b1 = -1e30f, b2 = -1e30f;
        for (int e = 0; e < Ee; e++) {
            float s = sc[e];
            if (s > b1) { b2 = b1; e2 = e1; b1 = s; e1 = e; }
            else if (s > b2) { b2 = s; e2 = e; }
        }
        float p1 = 1.f / (1.f + expf(b2 - b1));
        float p2 = 1.f - p1;
        tok_idx[t * 2 + 0] = e1;
        tok_idx[t * 2 + 1] = e2;
        tok_prob[t * 2 + 0] = p1;
        tok_prob[t * 2 + 1] = p2;
    }
}

// ---------------- route: fused count + scan + stable scatter, one block ----------------
// 1024 threads x 8 items = 8192 (t,k) assignments. No global atomics, deterministic.
__global__ __launch_bounds__(1024) void route_kernel(
    const int* __restrict__ tok_idx, const float* __restrict__ tok_prob,
    int* __restrict__ meta, int* __restrict__ list_tok,
    float* __restrict__ list_prob) {
    int tid = threadIdx.x;
    int lane = tid & 63, w = tid >> 6;   // 16 waves

    int e_loc[8];
#pragma unroll
    for (int j = 0; j < 8; j++) e_loc[j] = tok_idx[tid * 8 + j];

    // private histogram (static indexing only)
    int h[Ee];
#pragma unroll
    for (int e = 0; e < Ee; e++) {
        int c = 0;
#pragma unroll
        for (int j = 0; j < 8; j++) c += (e_loc[j] == e) ? 1 : 0;
        h[e] = c;
    }

    // per-expert exclusive prefix across the wave's 64 lanes + wave totals
    int pre[Ee], tot[Ee];
#pragma unroll
    for (int e = 0; e < Ee; e++) {
        int v = h[e];
        for (int d = 1; d < 64; d <<= 1) {
            int u = __shfl_up(v, d, 64);
            if (lane >= d) v += u;
        }
        pre[e] = v - h[e];
        tot[e] = __shfl(v, 63, 64);
    }

    __shared__ int wtot[16][Ee];
    __shared__ int wbase[16][Ee];
    __shared__ int ebase[Ee];
    if (lane == 0)
#pragma unroll
        for (int e = 0; e < Ee; e++) wtot[w][e] = tot[e];
    __syncthreads();
    if (tid == 0) {
        int etot[Ee];
        for (int e = 0; e < Ee; e++) {
            int s = 0;
            for (int ww = 0; ww < 16; ww++) { wbase[ww][e] = s; s += wtot[ww][e]; }
            etot[e] = s;
        }
        int b = 0;
        for (int e = 0; e < Ee; e++) {
            ebase[e] = b;
            meta[e] = etot[e];       // counts
            meta[16 + e] = b;        // bases
            b += etot[e];
        }
    }
    __syncthreads();

    int off[Ee];
#pragma unroll
    for (int e = 0; e < Ee; e++) off[e] = ebase[e] + wbase[w][e] + pre[e];

#pragma unroll
    for (int j = 0; j < 8; j++) {
        int item = tid * 8 + j;
        int el = e_loc[j];
        int pos = 0;
#pragma unroll
        for (int e = 0; e < Ee; e++) {
            if (el == e) { pos = off[e]; off[e] = pos + 1; }
        }
        list_tok[pos] = item >> 1;
        list_prob[pos] = tok_prob[item];
    }
}

// ---------------- fp32 -> bf16 convert ----------------
__global__ void cvt_kernel(const float* __restrict__ src, unsigned short* __restrict__ dst, int n4) {
    int i = blockIdx.x * blockDim.x + threadIdx.x;
    if (i >= n4) return;
    float4 v = reinterpret_cast<const float4*>(src)[i];
    uint2 o;
    o.x = (unsigned)f2bf(v.x) | ((unsigned)f2bf(v.y) << 16);
    o.y = (unsigned)f2bf(v.z) | ((unsigned)f2bf(v.w) << 16);
    reinterpret_cast<uint2*>(dst)[i] = o;
}

// ---------------- manual fp32->bf16 LDS staging (fallback path only, linear) ----------------
__device__ __forceinline__ void stage16(unsigned short* dst, const float* src) {
    const float4* s = reinterpret_cast<const float4*>(src);
    float4 v0 = s[0], v1 = s[1], v2 = s[2], v3 = s[3];
    uint4 o0, o1;
    o0.x = (unsigned)f2bf(v0.x) | ((unsigned)f2bf(v0.y) << 16);
    o0.y = (unsigned)f2bf(v0.z) | ((unsigned)f2bf(v0.w) << 16);
    o0.z = (unsigned)f2bf(v1.x) | ((unsigned)f2bf(v1.y) << 16);
    o0.w = (unsigned)f2bf(v1.z) | ((unsigned)f2bf(v1.w) << 16);
    o1.x = (unsigned)f2bf(v2.x) | ((unsigned)f2bf(v2.y) << 16);
    o1.y = (unsigned)f2bf(v2.z) | ((unsigned)f2bf(v2.w) << 16);
    o1.z = (unsigned)f2bf(v3.x) | ((unsigned)f2bf(v3.y) << 16);
    o1.w = (unsigned)f2bf(v3.z) | ((unsigned)f2bf(v3.w) << 16);
    uint4* d = reinterpret_cast<uint4*>(dst);
    d[0] = o0;
    d[1] = o1;
}

// ============ fused gemm1: hidden = silu(x W1^T) * (x W2^T) ============
// 256x128 tile (BMxBN), BK=32, 512 thr / 8 waves (2Mx4N), per-wave 128x32 dual.
// 1D grid: expert = bid&7 (pins each expert to one XCD under round-robin);
// tile = bid>>3: mblk = t>>4 (16), nblk = t&15 (16).
// Counted-vmcnt 2-deep pipeline: 4 loads/thread/K-step, wait vmcnt(4).
__global__ __launch_bounds__(512, 2) void rgemm12_kernel(
    const unsigned short* __restrict__ A,      // xb
    const unsigned short* __restrict__ B1w,    // W1b
    const unsigned short* __restrict__ B2w,    // W2b
    unsigned short* __restrict__ hout,         // hidden (bf16)
    const int* __restrict__ list_tok, const int* __restrict__ meta) {
    int bid = blockIdx.x;
    int e = bid & 7;
    int t = bid >> 3;
    int mblk = t >> 4, nblk = t & 15;
    int cnt = meta[e];
    int m0 = mblk * 256;
    if (m0 >= cnt) return;
    int bs = meta[16 + e];
    int n0 = nblk * 128;

    __shared__ unsigned short sA[2 * 256 * 32];    // 32 KB
    __shared__ unsigned short sB1[2 * 128 * 32];   // 16 KB
    __shared__ unsigned short sB2[2 * 128 * 32];   // 16 KB

    int tid = threadIdx.x;
    int lane = tid & 63, w = tid >> 6;             // 8 waves
    int wm = w >> 2, wn = w & 3;                   // 2M x 4N
    int lane15 = lane & 15, quad = lane >> 4;

    // staging: wave w owns A rows [w*32, w*32+32) (2 calls), B rows [w*16, w*16+16).
    int jrA = w * 32 + (lane >> 2);
    int jrB = w * 16 + (lane >> 2);
    // swizzled source chunk: chunk ^= (row>>1)&3; for all staging rows here
    // (row>>1)&3 == (lane>>3)&3 (w*32>>1, w*16>>1 both ≡ 0 mod 4).
    int c8 = (((lane & 3) ^ ((lane >> 3) & 3)) * 8);
    unsigned short* ldsA0 = sA + w * 1024;
    unsigned short* ldsA1 = ldsA0 + 512;
    unsigned short* ldsB1d = sB1 + w * 512;
    unsigned short* ldsB2d = sB2 + w * 512;

    int r0 = m0 + jrA;      if (r0 >= cnt) r0 = cnt - 1;
    int r1 = m0 + jrA + 16; if (r1 >= cnt) r1 = cnt - 1;
    const unsigned short* a0 = A + (size_t)list_tok[bs + r0] * Dd + c8;
    const unsigned short* a1 = A + (size_t)list_tok[bs + r1] * Dd + c8;
    const unsigned short* b1p = B1w + ((size_t)e * Ff + n0 + jrB) * Dd + c8;
    const unsigned short* b2p = B2w + ((size_t)e * Ff + n0 + jrB) * Dd + c8;

    // read-side swizzle: fragment row = (multiple of 16) + lane15 ->
    // (row>>1)&3 == (lane15>>1)&3, folds into the base pointer.
    int rsw = (lane15 >> 1) & 3;
    const unsigned short* sAr  = &sA [(wm * 128 + lane15) * 32 + (quad ^ rsw) * 8];
    const unsigned short* sB1r = &sB1[(wn * 32 + lane15) * 32 + (quad ^ rsw) * 8];
    const unsigned short* sB2r = &sB2[(wn * 32 + lane15) * 32 + (quad ^ rsw) * 8];

    floatx4 acc1[8][2] = {};
    floatx4 acc2[8][2] = {};

    // prologue: stage tiles 0 and 1 (8 loads/thread in flight)
#pragma unroll
    for (int p = 0; p < 2; p++) {
        int k = p * 32, oA = p * 8192, oB = p * 4096;
        gload16(a0 + k, ldsA0 + oA);
        gload16(a1 + k, ldsA1 + oA);
        gload16(b1p + k, ldsB1d + oB);
        gload16(b2p + k, ldsB2d + oB);
    }

    int cur = 0;
    for (int kt = 0; kt < 32; ++kt) {
        if (kt < 31) asm volatile("s_waitcnt vmcnt(4)" ::: "memory");
        else         asm volatile("s_waitcnt vmcnt(0)" ::: "memory");
        __builtin_amdgcn_s_barrier();
        asm volatile("" ::: "memory");

        int oA = cur * 8192, oB = cur * 4096;
        short8 af[8], b1f[2], b2f[2];
#pragma unroll
        for (int i = 0; i < 8; i++)
            af[i] = *reinterpret_cast<const short8*>(sAr + oA + i * 16 * 32);
#pragma unroll
        for (int i = 0; i < 2; i++) {
            b1f[i] = *reinterpret_cast<const short8*>(sB1r + oB + i * 16 * 32);
            b2f[i] = *reinterpret_cast<const short8*>(sB2r + oB + i * 16 * 32);
        }
        __builtin_amdgcn_s_setprio(1);
#pragma unroll
        for (int mi = 0; mi < 8; mi++)
#pragma unroll
            for (int ni = 0; ni < 2; ni++) {
                acc1[mi][ni] = __builtin_amdgcn_mfma_f32_16x16x32_bf16(af[mi], b1f[ni], acc1[mi][ni], 0, 0, 0);
                acc2[mi][ni] = __builtin_amdgcn_mfma_f32_16x16x32_bf16(af[mi], b2f[ni], acc2[mi][ni], 0, 0, 0);
            }
        __builtin_amdgcn_s_setprio(0);
        asm volatile("" ::: "memory");
        __builtin_amdgcn_s_barrier();   // all waves done reading buf[cur]
        asm volatile("" ::: "memory");
        if (kt + 2 < 32) {              // restage buf[cur] with tile kt+2
            int k = (kt + 2) * 32;
            gload16(a0 + k, ldsA0 + oA);
            gload16(a1 + k, ldsA1 + oA);
            gload16(b1p + k, ldsB1d + oB);
            gload16(b2p + k, ldsB2d + oB);
        }
        cur ^= 1;
    }

    // epilogue: hidden = silu(h1) * h2 on fp32 acc
#pragma unroll
    for (int mi = 0; mi < 8; mi++) {
#pragma unroll
        for (int i = 0; i < 4; i++) {
            int rr = m0 + wm * 128 + mi * 16 + quad * 4 + i;
            if (rr < cnt) {
                int pos = bs + rr;
                unsigned short* hp = hout + (size_t)pos * Ff + n0 + wn * 32;
#pragma unroll
                for (int ni = 0; ni < 2; ni++) {
                    float h1 = acc1[mi][ni][i];
                    float h2 = acc2[mi][ni][i];
                    float hv = h1 / (1.f + expf(-h1)) * h2;
                    hp[ni * 16 + lane15] = f2bf(hv);
                }
            }
        }
    }
}

// ============ gemm2 + combine: out[tok] += prob * (hidden W3^T) ============
// 256x128 tile over (pairs x Dd), AK=Ff=2048. Same geometry as rgemm12, single acc.
// 1D grid: expert = bid&7; t = bid>>3: mblk = t>>3 (16), nblk = t&7 (8).
__global__ __launch_bounds__(512, 2) void rg2_kernel(
    const unsigned short* __restrict__ A,      // hidden
    const unsigned short* __restrict__ B3,     // W3b  (e, d, f)
    float* __restrict__ out,                   // token-indexed atomic output
    const int* __restrict__ list_tok, const float* __restrict__ list_prob,
    const int* __restrict__ meta) {
    int bid = blockIdx.x;
    int e = bid & 7;
    int t = bid >> 3;
    int mblk = t >> 3, nblk = t & 7;
    int cnt = meta[e];
    int m0 = mblk * 256;
    if (m0 >= cnt) return;
    int bs = meta[16 + e];
    int n0 = nblk * 128;

    __shared__ unsigned short sA[2 * 256 * 32];    // 32 KB
    __shared__ unsigned short sB[2 * 128 * 32];    // 16 KB

    int tid = threadIdx.x;
    int lane = tid & 63, w = tid >> 6;
    int wm = w >> 2, wn = w & 3;
    int lane15 = lane & 15, quad = lane >> 4;

    int jrA = w * 32 + (lane >> 2);
    int jrB = w * 16 + (lane >> 2);
    int c8 = (((lane & 3) ^ ((lane >> 3) & 3)) * 8);
    unsigned short* ldsA0 = sA + w * 1024;
    unsigned short* ldsA1 = ldsA0 + 512;
    unsigned short* ldsBd = sB + w * 512;

    int r0 = m0 + jrA;      if (r0 >= cnt) r0 = cnt - 1;
    int r1 = m0 + jrA + 16; if (r1 >= cnt) r1 = cnt - 1;
    const unsigned short* a0 = A + (size_t)(bs + r0) * Ff + c8;   // rows contiguous
    const unsigned short* a1 = A + (size_t)(bs + r1) * Ff + c8;
    const unsigned short* bp = B3 + ((size_t)e * Dd + n0 + jrB) * Ff + c8;

    int rsw = (lane15 >> 1) & 3;
    const unsigned short* sAr = &sA[(wm * 128 + lane15) * 32 + (quad ^ rsw) * 8];
    const unsigned short* sBr = &sB[(wn * 32 + lane15) * 32 + (quad ^ rsw) * 8];

    floatx4 acc[8][2] = {};

    // prologue: stage tiles 0 and 1 (6 loads/thread in flight)
#pragma unroll
    for (int p = 0; p < 2; p++) {
        int k = p * 32, oA = p * 8192, oB = p * 4096;
        gload16(a0 + k, ldsA0 + oA);
        gload16(a1 + k, ldsA1 + oA);
        gload16(bp + k, ldsBd + oB);
    }

    int cur = 0;
    for (int kt = 0; kt < 64; ++kt) {
        if (kt < 63) asm volatile("s_waitcnt vmcnt(3)" ::: "memory");
        else         asm volatile("s_waitcnt vmcnt(0)" ::: "memory");
        __builtin_amdgcn_s_barrier();
        asm volatile("" ::: "memory");

        int oA = cur * 8192, oB = cur * 4096;
        short8 af[8], bfr[2];
#pragma unroll
        for (int i = 0; i < 8; i++)
            af[i] = *reinterpret_cast<const short8*>(sAr + oA + i * 16 * 32);
#pragma unroll
        for (int i = 0; i < 2; i++)
            bfr[i] = *reinterpret_cast<const short8*>(sBr + oB + i * 16 * 32);
        __builtin_amdgcn_s_setprio(1);
#pragma unroll
        for (int mi = 0; mi < 8; mi++)
#pragma unroll
            for (int ni = 0; ni < 2; ni++)
                acc[mi][ni] = __builtin_amdgcn_mfma_f32_16x16x32_bf16(af[mi], bfr[ni], acc[mi][ni], 0, 0, 0);
        __builtin_amdgcn_s_setprio(0);
        asm volatile("" ::: "memory");
        __builtin_amdgcn_s_barrier();
        asm volatile("" ::: "memory");
        if (kt + 2 < 64) {
            int k = (kt + 2) * 32;
            gload16(a0 + k, ldsA0 + oA);
            gload16(a1 + k, ldsA1 + oA);
            gload16(bp + k, ldsBd + oB);
        }
        cur ^= 1;
    }

    // epilogue: fused combine (exactly 2 contributions per out element)
#pragma unroll
    for (int mi = 0; mi < 8; mi++) {
#pragma unroll
        for (int i = 0; i < 4; i++) {
            int rr = m0 + wm * 128 + mi * 16 + quad * 4 + i;
            if (rr < cnt) {
                int pos = bs + rr;
                int tok = list_tok[pos];
                float p = list_prob[pos];
                float* yp = out + (size_t)tok * Dd + n0 + wn * 32;
#pragma unroll
                for (int ni = 0; ni < 2; ni++)
                    atomicAdd(&yp[ni * 16 + lane15], p * acc[mi][ni][i]);
            }
        }
    }
}

// ============ fallback routed GEMM (fp32 weights, 128x128, correctness-first) ============
template <typename WT, int EPI>
__global__ __launch_bounds__(256) void rgemm_kernel(
    const unsigned short* __restrict__ A,
    const WT* __restrict__ Bw,
    unsigned short* __restrict__ h1raw,
    unsigned short* __restrict__ hout,
    float* __restrict__ out,
    const int* __restrict__ list_tok, const float* __restrict__ list_prob,
    const int* __restrict__ meta,
    int AK, int BN, int arow_is_list) {
    constexpr bool BF = (sizeof(WT) == 2);
    int e = blockIdx.z;
    int cnt = meta[e];
    int m0 = blockIdx.y * 128;
    if (m0 >= cnt) return;
    int bs = meta[16 + e];
    int n0 = blockIdx.x * 128;

    __shared__ unsigned short sA[2 * 128 * 32];
    __shared__ unsigned short sB[2 * 128 * 32];

    int tid = threadIdx.x;
    int lane = tid & 63, w = tid >> 6;
    int wm = w >> 1, wn = w & 1;
    int lane15 = lane & 15, quad = lane >> 4;

    int jr = w * 32 + (lane >> 2);
    int c8 = (lane & 3) * 8;
    unsigned short* ldsA0 = sA + w * 1024;
    unsigned short* ldsA1 = ldsA0 + 512;

    int r0 = m0 + jr;      if (r0 >= cnt) r0 = cnt - 1;
    int r1 = m0 + jr + 16; if (r1 >= cnt) r1 = cnt - 1;
    size_t ar0 = arow_is_list ? (size_t)list_tok[bs + r0] : (size_t)(bs + r0);
    size_t ar1 = arow_is_list ? (size_t)list_tok[bs + r1] : (size_t)(bs + r1);
    const unsigned short* a0 = A + ar0 * AK + c8;
    const unsigned short* a1 = A + ar1 * AK + c8;

    int row = tid >> 1, colb = (tid & 1) * 16;
    const WT* bmp = Bw + ((size_t)e * BN + n0 + row) * AK + colb;
    unsigned short* sBw = &sB[row * 32 + colb];

    const unsigned short* sAr = &sA[(wm * 64 + lane15) * 32 + quad * 8];
    const unsigned short* sBr = &sB[(wn * 64 + lane15) * 32 + quad * 8];

    floatx4 acc[4][4] = {};

    gload16(a0, ldsA0);
    gload16(a1, ldsA1);
    stage16(sBw, (const float*)bmp);
    __syncthreads();
    int cur = 0;
    for (int k0 = 0; k0 < AK; k0 += 32) {
        if (k0 + 32 < AK) {
            int o = (cur ^ 1) * 4096;
            int k = k0 + 32;
            gload16(a0 + k, ldsA0 + o);
            gload16(a1 + k, ldsA1 + o);
            stage16(sBw + o, (const float*)(bmp + k));
        }
        int o = cur * 4096;
        short8 af[4], bfr[4];
#pragma unroll
        for (int i = 0; i < 4; i++) {
            af[i]  = *reinterpret_cast<const short8*>(sAr + o + i * 16 * 32);
            bfr[i] = *reinterpret_cast<const short8*>(sBr + o + i * 16 * 32);
        }
#pragma unroll
        for (int mi = 0; mi < 4; mi++)
#pragma unroll
            for (int ni = 0; ni < 4; ni++)
                acc[mi][ni] = __builtin_amdgcn_mfma_f32_16x16x32_bf16(af[mi], bfr[ni], acc[mi][ni], 0, 0, 0);
        __syncthreads();
        cur ^= 1;
    }

#pragma unroll
    for (int mi = 0; mi < 4; mi++) {
#pragma unroll
        for (int i = 0; i < 4; i++) {
            int rr = m0 + wm * 64 + mi * 16 + quad * 4 + i;
            if (rr < cnt) {
                int pos = bs + rr;
                if constexpr (EPI == 0) {
                    unsigned short* hp = h1raw + (size_t)pos * BN + n0 + wn * 64;
#pragma unroll
                    for (int ni = 0; ni < 4; ni++)
                        hp[ni * 16 + lane15] = f2bf(acc[mi][ni][i]);
                } else if constexpr (EPI == 1) {
                    const unsigned short* h1p = h1raw + (size_t)pos * BN + n0 + wn * 64;
                    unsigned short* hp = hout + (size_t)pos * BN + n0 + wn * 64;
#pragma unroll
                    for (int ni = 0; ni < 4; ni++) {
                        float h1 = bf2f(h1p[ni * 16 + lane15]);
                        float h2 = acc[mi][ni][i];
                        float hv = h1 / (1.f + expf(-h1)) * h2;
                        hp[ni * 16 + lane15] = f2bf(hv);
                    }
                } else {
                    int tok = list_tok[pos];
                    float p = list_prob[pos];
                    float* yp = out + (size_t)tok * BN + n0 + wn * 64;
#pragma unroll
                    for (int ni = 0; ni < 4; ni++)
                        atomicAdd(&yp[ni * 16 + lane15], p * acc[mi][ni][i]);
                }
            }
        }
    }
}

// ---------------- host launch ----------------
extern "C" void kernel_launch(void* const* d_in, const int* in_sizes, int n_in,
                              void* d_out, int out_size, void* d_ws, size_t ws_size,
                              hipStream_t stream) {
    const float* x  = (const float*)d_in[0];
    const float* Wg = (const float*)d_in[1];
    const float* W1 = (const float*)d_in[2];
    const float* W2 = (const float*)d_in[3];
    const float* W3 = (const float*)d_in[4];
    float* out = (float*)d_out;

    char* ws = (char*)d_ws;
    size_t off = 0;
    auto alloc = [&](size_t bytes) -> char* {
        size_t o = off;
        off += (bytes + 255) & ~(size_t)255;
        return ws + o;
    };

    int* meta = (int*)alloc(64 * sizeof(int));
    int* tok_idx = (int*)alloc((size_t)TOK * 2 * sizeof(int));
    float* tok_prob = (float*)alloc((size_t)TOK * 2 * sizeof(float));
    int* list_tok = (int*)alloc((size_t)PAIRS * sizeof(int));
    float* list_prob = (float*)alloc((size_t)PAIRS * sizeof(float));
    unsigned short* xb = (unsigned short*)alloc((size_t)TOK * Dd * sizeof(unsigned short));
    unsigned short* hidden = (unsigned short*)alloc((size_t)PAIRS * Ff * sizeof(unsigned short));
    unsigned short* h1raw = (unsigned short*)alloc((size_t)PAIRS * Ff * sizeof(unsigned short));  // fallback path only

    // bf16 weight copies
    size_t wbytes = (size_t)Ee * Ff * Dd * sizeof(unsigned short);
    bool has_w = (ws_size >= off + 3 * wbytes + 4096);
    unsigned short *W1b = nullptr, *W2b = nullptr, *W3b = nullptr;
    if (has_w) {
        W1b = (unsigned short*)alloc(wbytes);
        W2b = (unsigned short*)alloc(wbytes);
        W3b = (unsigned short*)alloc(wbytes);
    }

    // out pre-zeroed for the atomic-accumulate epilogue
    zero_kernel<<<dim3(TOK * Dd / 4 / 256), dim3(256), 0, stream>>>(out, TOK * Dd / 4);

    gating_kernel<<<dim3(TOK / 4), dim3(256), 0, stream>>>(x, Wg, tok_idx, tok_prob);
    route_kernel<<<dim3(1), dim3(1024), 0, stream>>>(tok_idx, tok_prob, meta,
                                                     list_tok, list_prob);

    int xn4 = TOK * Dd / 4;
    cvt_kernel<<<dim3((xn4 + 255) / 256), dim3(256), 0, stream>>>(x, xb, xn4);

    if (has_w) {
        dim3 blk(256);
        int wn4 = Ee * Ff * Dd / 4;
        cvt_kernel<<<dim3((wn4 + 255) / 256), blk, 0, stream>>>(W1, W1b, wn4);
        cvt_kernel<<<dim3((wn4 + 255) / 256), blk, 0, stream>>>(W2, W2b, wn4);
        cvt_kernel<<<dim3((wn4 + 255) / 256), blk, 0, stream>>>(W3, W3b, wn4);
        // fused gemm1: hidden = silu(x W1^T) * (x W2^T); expert pinned per XCD
        rgemm12_kernel<<<dim3(8 * 16 * 16), dim3(512), 0, stream>>>(
            xb, W1b, W2b, hidden, list_tok, meta);
        // gemm2 + combine
        rg2_kernel<<<dim3(8 * 16 * 8), dim3(512), 0, stream>>>(
            hidden, W3b, out, list_tok, list_prob, meta);
    } else {
        dim3 g1(Ff / 128, 32, Ee), g2(Dd / 128, 32, Ee), blk(256);
        rgemm_kernel<float, 0><<<g1, blk, 0, stream>>>(
            xb, W1, h1raw, nullptr, nullptr, list_tok, list_prob, meta, Dd, Ff, 1);
        rgemm_kernel<float, 1><<<g1, blk, 0, stream>>>(
            xb, W2, h1raw, hidden, nullptr, list_tok, list_prob, meta, Dd, Ff, 1);
        rgemm_kernel<float, 2><<<g2, blk, 0, stream>>>(
            hidden, W3, nullptr, nullptr, out, list_tok, list_prob, meta, Ff, Dd, 0);
    }
}

// Round 5
// 448.322 us; speedup vs baseline: 1.0994x; 1.0994x over previous
//
#include <hip/hip_runtime.h>
#include <hip/hip_bf16.h>
#include <cstdint>

// MoE feed-forward, routed top-2 of 8 experts.
// B=2 S=2048 D=1024 F=2048 E=8 K=2.
// R10: REVERT R9 geometry (256x128/8-wave regressed: worse per-wave MFMA:LDS
//   shape, 2 blocks/CU, occupancy collapse). Back to R8's 128x128/4-wave
//   structure byte-for-byte, plus ONE change: L2-locality block swizzle.
//   Evidence: staging throughput plateaus at ~6.4 TB/s across R5/R6/R8
//   schedules (768 MB/119us) and pipelining was null twice -> L3/fabric
//   BW-bound. Fix locality, not overlap:
//   - gemm1: groups (e,nblk); 32 mblk-members consecutive on one XCD share
//     the 512 KB B1/B2 panel via L2 -> B L3 traffic 512->~64 MB.
//   - gemm2: groups (e,mblk); 8 nblk-members share the hidden A panel
//     -> A L3 traffic 256->~32 MB.
//   Per-XCD load identical by construction (each expert: 2 groups/XCD).
//   (kept: dual-acc fused gemm1, XOR chunk swizzle -> 0 bank conflicts,
//    counted-vmcnt pipeline, atomic combine, no-atomic routing)

#define Dd 1024
#define Ff 2048
#define Ee 8
#define TOK 4096
#define PAIRS 8192

typedef __attribute__((ext_vector_type(8))) short short8;
typedef __attribute__((ext_vector_type(4))) float floatx4;

__device__ __forceinline__ unsigned short f2bf(float f) {
    unsigned int u = __float_as_uint(f);
    unsigned int r = (u + 0x7FFFu + ((u >> 16) & 1u)) >> 16;
    return (unsigned short)r;
}
__device__ __forceinline__ float bf2f(unsigned short u) {
    return __uint_as_float(((unsigned)u) << 16);
}

// async 16B/lane global->LDS. lds ptr is wave-uniform; lane i lands at lds + i*16B.
__device__ __forceinline__ void gload16(const unsigned short* g, unsigned short* l) {
    __builtin_amdgcn_global_load_lds(
        (const __attribute__((address_space(1))) unsigned int*)g,
        (__attribute__((address_space(3))) unsigned int*)l,
        16, 0, 0);
}

// ---------------- zero out ----------------
__global__ void zero_kernel(float* __restrict__ out, int n4) {
    int i = blockIdx.x * blockDim.x + threadIdx.x;
    if (i < n4) reinterpret_cast<float4*>(out)[i] = make_float4(0.f, 0.f, 0.f, 0.f);
}

// ---------------- gating: fp32 scores, top-2, softmax (NO atomics) ----------------
__global__ void gating_kernel(const float* __restrict__ x, const float* __restrict__ Wg,
                              int* __restrict__ tok_idx, float* __restrict__ tok_prob) {
    int lane = threadIdx.x & 63;
    int w = threadIdx.x >> 6;
    int t = blockIdx.x * 4 + w;

    float xr[16];
    const float* xp = x + (size_t)t * Dd;
#pragma unroll
    for (int i = 0; i < 16; i++) xr[i] = xp[lane + i * 64];

    float sc[Ee];
    for (int e = 0; e < Ee; e++) {
        const float* wp = Wg + (size_t)e * Dd;
        float p = 0.f;
#pragma unroll
        for (int i = 0; i < 16; i++) p += xr[i] * wp[lane + i * 64];
        for (int off = 32; off > 0; off >>= 1) p += __shfl_xor(p, off);
        sc[e] = p;
    }
    if (lane == 0) {
        int e1 = 0, e2 = 0;
        float b1 = -1e30f, b2 = -1e30f;
        for (int e = 0; e < Ee; e++) {
            float s = sc[e];
            if (s > b1) { b2 = b1; e2 = e1; b1 = s; e1 = e; }
            else if (s > b2) { b2 = s; e2 = e; }
        }
        float p1 = 1.f / (1.f + expf(b2 - b1));
        float p2 = 1.f - p1;
        tok_idx[t * 2 + 0] = e1;
        tok_idx[t * 2 + 1] = e2;
        tok_prob[t * 2 + 0] = p1;
        tok_prob[t * 2 + 1] = p2;
    }
}

// ---------------- route: fused count + scan + stable scatter, one block ----------------
// 1024 threads x 8 items = 8192 (t,k) assignments. No global atomics, deterministic.
__global__ __launch_bounds__(1024) void route_kernel(
    const int* __restrict__ tok_idx, const float* __restrict__ tok_prob,
    int* __restrict__ meta, int* __restrict__ list_tok,
    float* __restrict__ list_prob) {
    int tid = threadIdx.x;
    int lane = tid & 63, w = tid >> 6;   // 16 waves

    int e_loc[8];
#pragma unroll
    for (int j = 0; j < 8; j++) e_loc[j] = tok_idx[tid * 8 + j];

    // private histogram (static indexing only)
    int h[Ee];
#pragma unroll
    for (int e = 0; e < Ee; e++) {
        int c = 0;
#pragma unroll
        for (int j = 0; j < 8; j++) c += (e_loc[j] == e) ? 1 : 0;
        h[e] = c;
    }

    // per-expert exclusive prefix across the wave's 64 lanes + wave totals
    int pre[Ee], tot[Ee];
#pragma unroll
    for (int e = 0; e < Ee; e++) {
        int v = h[e];
        for (int d = 1; d < 64; d <<= 1) {
            int u = __shfl_up(v, d, 64);
            if (lane >= d) v += u;
        }
        pre[e] = v - h[e];
        tot[e] = __shfl(v, 63, 64);
    }

    __shared__ int wtot[16][Ee];
    __shared__ int wbase[16][Ee];
    __shared__ int ebase[Ee];
    if (lane == 0)
#pragma unroll
        for (int e = 0; e < Ee; e++) wtot[w][e] = tot[e];
    __syncthreads();
    if (tid == 0) {
        int etot[Ee];
        for (int e = 0; e < Ee; e++) {
            int s = 0;
            for (int ww = 0; ww < 16; ww++) { wbase[ww][e] = s; s += wtot[ww][e]; }
            etot[e] = s;
        }
        int b = 0;
        for (int e = 0; e < Ee; e++) {
            ebase[e] = b;
            meta[e] = etot[e];       // counts
            meta[16 + e] = b;        // bases
            b += etot[e];
        }
    }
    __syncthreads();

    int off[Ee];
#pragma unroll
    for (int e = 0; e < Ee; e++) off[e] = ebase[e] + wbase[w][e] + pre[e];

#pragma unroll
    for (int j = 0; j < 8; j++) {
        int item = tid * 8 + j;
        int el = e_loc[j];
        int pos = 0;
#pragma unroll
        for (int e = 0; e < Ee; e++) {
            if (el == e) { pos = off[e]; off[e] = pos + 1; }
        }
        list_tok[pos] = item >> 1;
        list_prob[pos] = tok_prob[item];
    }
}

// ---------------- fp32 -> bf16 convert ----------------
__global__ void cvt_kernel(const float* __restrict__ src, unsigned short* __restrict__ dst, int n4) {
    int i = blockIdx.x * blockDim.x + threadIdx.x;
    if (i >= n4) return;
    float4 v = reinterpret_cast<const float4*>(src)[i];
    uint2 o;
    o.x = (unsigned)f2bf(v.x) | ((unsigned)f2bf(v.y) << 16);
    o.y = (unsigned)f2bf(v.z) | ((unsigned)f2bf(v.w) << 16);
    reinterpret_cast<uint2*>(dst)[i] = o;
}

// ---------------- manual fp32->bf16 LDS staging (fallback path only, linear) ----------------
__device__ __forceinline__ void stage16(unsigned short* dst, const float* src) {
    const float4* s = reinterpret_cast<const float4*>(src);
    float4 v0 = s[0], v1 = s[1], v2 = s[2], v3 = s[3];
    uint4 o0, o1;
    o0.x = (unsigned)f2bf(v0.x) | ((unsigned)f2bf(v0.y) << 16);
    o0.y = (unsigned)f2bf(v0.z) | ((unsigned)f2bf(v0.w) << 16);
    o0.z = (unsigned)f2bf(v1.x) | ((unsigned)f2bf(v1.y) << 16);
    o0.w = (unsigned)f2bf(v1.z) | ((unsigned)f2bf(v1.w) << 16);
    o1.x = (unsigned)f2bf(v2.x) | ((unsigned)f2bf(v2.y) << 16);
    o1.y = (unsigned)f2bf(v2.z) | ((unsigned)f2bf(v2.w) << 16);
    o1.z = (unsigned)f2bf(v3.x) | ((unsigned)f2bf(v3.y) << 16);
    o1.w = (unsigned)f2bf(v3.z) | ((unsigned)f2bf(v3.w) << 16);
    uint4* d = reinterpret_cast<uint4*>(dst);
    d[0] = o0;
    d[1] = o1;
}

// ============ fused gemm1: hidden = silu(x W1^T) * (x W2^T), routed rows ============
// R8 structure: 128x128 tile, BK=32, 4 waves (2Mx2N, 64x64/wave), dual acc.
// Counted-vmcnt 2-deep pipeline (vmcnt(6)). XOR chunk swizzle both sides.
// R10: 1D grid with L2-locality swizzle. group g = e*16+nblk (128 groups);
// members = 32 mblks, consecutive on XCD (bid&7) -> B1/B2 panel (512 KB)
// is read from L3 once per group, L2-hits for the other members.
__global__ __launch_bounds__(256, 2) void rgemm12_kernel(
    const unsigned short* __restrict__ A,      // xb
    const unsigned short* __restrict__ B1w,    // W1b
    const unsigned short* __restrict__ B2w,    // W2b
    unsigned short* __restrict__ hout,         // hidden (bf16)
    const int* __restrict__ list_tok, const int* __restrict__ meta) {
    // decode swizzled 1D bid: bid = (g&7) + 8*((g>>3)*32 + mblk)
    int bid = blockIdx.x;
    int low3 = bid & 7;
    int s = bid >> 3;
    int mblk = s & 31;
    int g = ((s >> 5) << 3) + low3;    // 0..127
    int e = g >> 4;
    int nblk = g & 15;

    int cnt = meta[e];
    int m0 = mblk * 128;
    if (m0 >= cnt) return;
    int bs = meta[16 + e];
    int n0 = nblk * 128;

    __shared__ unsigned short sA[2 * 128 * 32];
    __shared__ unsigned short sB1[2 * 128 * 32];
    __shared__ unsigned short sB2[2 * 128 * 32];

    int tid = threadIdx.x;
    int lane = tid & 63, w = tid >> 6;
    int wm = w >> 1, wn = w & 1;
    int lane15 = lane & 15, quad = lane >> 4;

    // staging geometry: wave w stages rows [w*32, w*32+16) then +16.
    // swizzled source chunk: lane's row jr has (jr>>1)&3 == (lane>>3)&3.
    int jr = w * 32 + (lane >> 2);
    int c8 = (((lane & 3) ^ ((lane >> 3) & 3)) * 8);
    unsigned short* ldsA0  = sA  + w * 1024;
    unsigned short* ldsA1  = ldsA0 + 512;
    unsigned short* ldsB10 = sB1 + w * 1024;
    unsigned short* ldsB11 = ldsB10 + 512;
    unsigned short* ldsB20 = sB2 + w * 1024;
    unsigned short* ldsB21 = ldsB20 + 512;

    int r0 = m0 + jr;      if (r0 >= cnt) r0 = cnt - 1;
    int r1 = m0 + jr + 16; if (r1 >= cnt) r1 = cnt - 1;
    size_t ar0 = (size_t)list_tok[bs + r0];
    size_t ar1 = (size_t)list_tok[bs + r1];
    const unsigned short* a0 = A + ar0 * Dd + c8;
    const unsigned short* a1 = A + ar1 * Dd + c8;
    const unsigned short* b10 = B1w + ((size_t)e * Ff + n0 + jr) * Dd + c8;
    const unsigned short* b11 = b10 + (size_t)16 * Dd;
    const unsigned short* b20 = B2w + ((size_t)e * Ff + n0 + jr) * Dd + c8;
    const unsigned short* b21 = b20 + (size_t)16 * Dd;

    // read-side swizzle: fragment row is (..+lane15); (row>>1)&3 == (lane15>>1)&3,
    // independent of mi/wm -> folds into the base pointer.
    int rsw = (lane15 >> 1) & 3;
    const unsigned short* sAr  = &sA [(wm * 64 + lane15) * 32 + (quad ^ rsw) * 8];
    const unsigned short* sB1r = &sB1[(wn * 64 + lane15) * 32 + (quad ^ rsw) * 8];
    const unsigned short* sB2r = &sB2[(wn * 64 + lane15) * 32 + (quad ^ rsw) * 8];

    floatx4 acc1[4][4] = {};
    floatx4 acc2[4][4] = {};

    // prologue: stage tiles 0 and 1 (12 loads in flight)
#pragma unroll
    for (int t = 0; t < 2; t++) {
        int k = t * 32, o = t * 4096;
        gload16(a0 + k,  ldsA0  + o);
        gload16(a1 + k,  ldsA1  + o);
        gload16(b10 + k, ldsB10 + o);
        gload16(b11 + k, ldsB11 + o);
        gload16(b20 + k, ldsB20 + o);
        gload16(b21 + k, ldsB21 + o);
    }

    int cur = 0;
    for (int t = 0; t < 32; ++t) {
        // wait ONLY this tile's 6 loads (next tile's 6 stay in flight)
        if (t < 31) asm volatile("s_waitcnt vmcnt(6)" ::: "memory");
        else        asm volatile("s_waitcnt vmcnt(0)" ::: "memory");
        __builtin_amdgcn_s_barrier();
        asm volatile("" ::: "memory");

        int o = cur * 4096;
        short8 af[4], b1f[4], b2f[4];
#pragma unroll
        for (int i = 0; i < 4; i++) {
            af[i]  = *reinterpret_cast<const short8*>(sAr  + o + i * 16 * 32);
            b1f[i] = *reinterpret_cast<const short8*>(sB1r + o + i * 16 * 32);
            b2f[i] = *reinterpret_cast<const short8*>(sB2r + o + i * 16 * 32);
        }
        __builtin_amdgcn_s_setprio(1);
#pragma unroll
        for (int mi = 0; mi < 4; mi++)
#pragma unroll
            for (int ni = 0; ni < 4; ni++) {
                acc1[mi][ni] = __builtin_amdgcn_mfma_f32_16x16x32_bf16(af[mi], b1f[ni], acc1[mi][ni], 0, 0, 0);
                acc2[mi][ni] = __builtin_amdgcn_mfma_f32_16x16x32_bf16(af[mi], b2f[ni], acc2[mi][ni], 0, 0, 0);
            }
        __builtin_amdgcn_s_setprio(0);
        asm volatile("" ::: "memory");
        __builtin_amdgcn_s_barrier();   // all waves done reading buf[cur]
        asm volatile("" ::: "memory");
        if (t + 2 < 32) {               // restage buf[cur] with tile t+2
            int k = (t + 2) * 32;
            gload16(a0 + k,  ldsA0  + o);
            gload16(a1 + k,  ldsA1  + o);
            gload16(b10 + k, ldsB10 + o);
            gload16(b11 + k, ldsB11 + o);
            gload16(b20 + k, ldsB20 + o);
            gload16(b21 + k, ldsB21 + o);
        }
        cur ^= 1;
    }

    // epilogue: hidden = silu(h1) * h2, silu on full-precision acc
#pragma unroll
    for (int mi = 0; mi < 4; mi++) {
#pragma unroll
        for (int i = 0; i < 4; i++) {
            int rr = m0 + wm * 64 + mi * 16 + quad * 4 + i;
            if (rr < cnt) {
                int pos = bs + rr;
                unsigned short* hp = hout + (size_t)pos * Ff + n0 + wn * 64;
#pragma unroll
                for (int ni = 0; ni < 4; ni++) {
                    float h1 = acc1[mi][ni][i];
                    float h2 = acc2[mi][ni][i];
                    float hv = h1 / (1.f + expf(-h1)) * h2;
                    hp[ni * 16 + lane15] = f2bf(hv);
                }
            }
        }
    }
}

// ============ gemm2 + combine: out[tok] += prob * (hidden W3^T) ============
// R8 structure: 128x128 tile, 4 waves, single acc, vmcnt(4) pipeline.
// R10: 1D grid, group g = e*32+mblk (256 groups); members = 8 nblks share
// the 512 KB hidden A-panel via L2 on one XCD.
__global__ __launch_bounds__(256, 2) void rg2_kernel(
    const unsigned short* __restrict__ A,      // hidden
    const unsigned short* __restrict__ B3,     // W3b (e, d, f)
    float* __restrict__ out,                   // token-indexed atomic output
    const int* __restrict__ list_tok, const float* __restrict__ list_prob,
    const int* __restrict__ meta) {
    // decode: bid = (g&7) + 8*((g>>3)*8 + nblk)
    int bid = blockIdx.x;
    int low3 = bid & 7;
    int s = bid >> 3;
    int nblk = s & 7;
    int g = ((s >> 3) << 3) + low3;    // 0..255
    int e = g >> 5;
    int mblk = g & 31;

    int cnt = meta[e];
    int m0 = mblk * 128;
    if (m0 >= cnt) return;
    int bs = meta[16 + e];
    int n0 = nblk * 128;

    __shared__ unsigned short sA[2 * 128 * 32];
    __shared__ unsigned short sB[2 * 128 * 32];

    int tid = threadIdx.x;
    int lane = tid & 63, w = tid >> 6;
    int wm = w >> 1, wn = w & 1;
    int lane15 = lane & 15, quad = lane >> 4;

    int jr = w * 32 + (lane >> 2);
    int c8 = (((lane & 3) ^ ((lane >> 3) & 3)) * 8);
    unsigned short* ldsA0 = sA + w * 1024;
    unsigned short* ldsA1 = ldsA0 + 512;
    unsigned short* ldsB0 = sB + w * 1024;
    unsigned short* ldsB1 = ldsB0 + 512;

    int r0 = m0 + jr;      if (r0 >= cnt) r0 = cnt - 1;
    int r1 = m0 + jr + 16; if (r1 >= cnt) r1 = cnt - 1;
    const unsigned short* a0 = A + (size_t)(bs + r0) * Ff + c8;   // rows contiguous
    const unsigned short* a1 = A + (size_t)(bs + r1) * Ff + c8;
    const unsigned short* b0 = B3 + ((size_t)e * Dd + n0 + jr) * Ff + c8;
    const unsigned short* b1 = b0 + (size_t)16 * Ff;

    int rsw = (lane15 >> 1) & 3;
    const unsigned short* sAr = &sA[(wm * 64 + lane15) * 32 + (quad ^ rsw) * 8];
    const unsigned short* sBr = &sB[(wn * 64 + lane15) * 32 + (quad ^ rsw) * 8];

    floatx4 acc[4][4] = {};

    // prologue: stage tiles 0 and 1 (8 loads in flight)
#pragma unroll
    for (int t = 0; t < 2; t++) {
        int k = t * 32, o = t * 4096;
        gload16(a0 + k, ldsA0 + o);
        gload16(a1 + k, ldsA1 + o);
        gload16(b0 + k, ldsB0 + o);
        gload16(b1 + k, ldsB1 + o);
    }
    int cur = 0;
    const int NT = Ff / 32;   // 64
    for (int t = 0; t < NT; ++t) {
        if (t + 1 < NT) asm volatile("s_waitcnt vmcnt(4)" ::: "memory");
        else            asm volatile("s_waitcnt vmcnt(0)" ::: "memory");
        __builtin_amdgcn_s_barrier();
        asm volatile("" ::: "memory");

        int o = cur * 4096;
        short8 af[4], bfr[4];
#pragma unroll
        for (int i = 0; i < 4; i++) {
            af[i]  = *reinterpret_cast<const short8*>(sAr + o + i * 16 * 32);
            bfr[i] = *reinterpret_cast<const short8*>(sBr + o + i * 16 * 32);
        }
        __builtin_amdgcn_s_setprio(1);
#pragma unroll
        for (int mi = 0; mi < 4; mi++)
#pragma unroll
            for (int ni = 0; ni < 4; ni++)
                acc[mi][ni] = __builtin_amdgcn_mfma_f32_16x16x32_bf16(af[mi], bfr[ni], acc[mi][ni], 0, 0, 0);
        __builtin_amdgcn_s_setprio(0);
        asm volatile("" ::: "memory");
        __builtin_amdgcn_s_barrier();
        asm volatile("" ::: "memory");
        if (t + 2 < NT) {
            int k = (t + 2) * 32;
            gload16(a0 + k, ldsA0 + o);
            gload16(a1 + k, ldsA1 + o);
            gload16(b0 + k, ldsB0 + o);
            gload16(b1 + k, ldsB1 + o);
        }
        cur ^= 1;
    }

    // epilogue: fused combine (exactly 2 contributions per out element)
#pragma unroll
    for (int mi = 0; mi < 4; mi++) {
#pragma unroll
        for (int i = 0; i < 4; i++) {
            int rr = m0 + wm * 64 + mi * 16 + quad * 4 + i;
            if (rr < cnt) {
                int pos = bs + rr;
                int tok = list_tok[pos];
                float p = list_prob[pos];
                float* yp = out + (size_t)tok * Dd + n0 + wn * 64;
#pragma unroll
                for (int ni = 0; ni < 4; ni++)
                    atomicAdd(&yp[ni * 16 + lane15], p * acc[mi][ni][i]);
            }
        }
    }
}

// ============ fallback routed GEMM (fp32 weights, correctness-first) ============
template <int EPI>
__global__ __launch_bounds__(256) void rgemm_kernel(
    const unsigned short* __restrict__ A,
    const float* __restrict__ Bw,
    unsigned short* __restrict__ h1raw,
    unsigned short* __restrict__ hout,
    float* __restrict__ out,
    const int* __restrict__ list_tok, const float* __restrict__ list_prob,
    const int* __restrict__ meta,
    int AK, int BN, int arow_is_list) {
    int e = blockIdx.z;
    int cnt = meta[e];
    int m0 = blockIdx.y * 128;
    if (m0 >= cnt) return;
    int bs = meta[16 + e];
    int n0 = blockIdx.x * 128;

    __shared__ unsigned short sA[2 * 128 * 32];
    __shared__ unsigned short sB[2 * 128 * 32];

    int tid = threadIdx.x;
    int lane = tid & 63, w = tid >> 6;
    int wm = w >> 1, wn = w & 1;
    int lane15 = lane & 15, quad = lane >> 4;

    int jr = w * 32 + (lane >> 2);
    int c8 = (lane & 3) * 8;
    unsigned short* ldsA0 = sA + w * 1024;
    unsigned short* ldsA1 = ldsA0 + 512;

    int r0 = m0 + jr;      if (r0 >= cnt) r0 = cnt - 1;
    int r1 = m0 + jr + 16; if (r1 >= cnt) r1 = cnt - 1;
    size_t ar0 = arow_is_list ? (size_t)list_tok[bs + r0] : (size_t)(bs + r0);
    size_t ar1 = arow_is_list ? (size_t)list_tok[bs + r1] : (size_t)(bs + r1);
    const unsigned short* a0 = A + ar0 * AK + c8;
    const unsigned short* a1 = A + ar1 * AK + c8;

    int row = tid >> 1, colb = (tid & 1) * 16;
    const float* bmp = Bw + ((size_t)e * BN + n0 + row) * AK + colb;
    unsigned short* sBw = &sB[row * 32 + colb];

    const unsigned short* sAr = &sA[(wm * 64 + lane15) * 32 + quad * 8];
    const unsigned short* sBr = &sB[(wn * 64 + lane15) * 32 + quad * 8];

    floatx4 acc[4][4] = {};

    gload16(a0, ldsA0);
    gload16(a1, ldsA1);
    stage16(sBw, bmp);
    __syncthreads();
    int cur = 0;
    for (int k0 = 0; k0 < AK; k0 += 32) {
        if (k0 + 32 < AK) {
            int o = (cur ^ 1) * 4096;
            int k = k0 + 32;
            gload16(a0 + k, ldsA0 + o);
            gload16(a1 + k, ldsA1 + o);
            stage16(sBw + o, bmp + k);
        }
        int o = cur * 4096;
        short8 af[4], bfr[4];
#pragma unroll
        for (int i = 0; i < 4; i++) {
            af[i]  = *reinterpret_cast<const short8*>(sAr + o + i * 16 * 32);
            bfr[i] = *reinterpret_cast<const short8*>(sBr + o + i * 16 * 32);
        }
#pragma unroll
        for (int mi = 0; mi < 4; mi++)
#pragma unroll
            for (int ni = 0; ni < 4; ni++)
                acc[mi][ni] = __builtin_amdgcn_mfma_f32_16x16x32_bf16(af[mi], bfr[ni], acc[mi][ni], 0, 0, 0);
        __syncthreads();
        cur ^= 1;
    }

#pragma unroll
    for (int mi = 0; mi < 4; mi++) {
#pragma unroll
        for (int i = 0; i < 4; i++) {
            int rr = m0 + wm * 64 + mi * 16 + quad * 4 + i;
            if (rr < cnt) {
                int pos = bs + rr;
                if constexpr (EPI == 0) {
                    unsigned short* hp = h1raw + (size_t)pos * BN + n0 + wn * 64;
#pragma unroll
                    for (int ni = 0; ni < 4; ni++)
                        hp[ni * 16 + lane15] = f2bf(acc[mi][ni][i]);
                } else if constexpr (EPI == 1) {
                    const unsigned short* h1p = h1raw + (size_t)pos * BN + n0 + wn * 64;
                    unsigned short* hp = hout + (size_t)pos * BN + n0 + wn * 64;
#pragma unroll
                    for (int ni = 0; ni < 4; ni++) {
                        float h1 = bf2f(h1p[ni * 16 + lane15]);
                        float h2 = acc[mi][ni][i];
                        float hv = h1 / (1.f + expf(-h1)) * h2;
                        hp[ni * 16 + lane15] = f2bf(hv);
                    }
                } else {
                    int tok = list_tok[pos];
                    float p = list_prob[pos];
                    float* yp = out + (size_t)tok * BN + n0 + wn * 64;
#pragma unroll
                    for (int ni = 0; ni < 4; ni++)
                        atomicAdd(&yp[ni * 16 + lane15], p * acc[mi][ni][i]);
                }
            }
        }
    }
}

// ---------------- host launch ----------------
extern "C" void kernel_launch(void* const* d_in, const int* in_sizes, int n_in,
                              void* d_out, int out_size, void* d_ws, size_t ws_size,
                              hipStream_t stream) {
    const float* x  = (const float*)d_in[0];
    const float* Wg = (const float*)d_in[1];
    const float* W1 = (const float*)d_in[2];
    const float* W2 = (const float*)d_in[3];
    const float* W3 = (const float*)d_in[4];
    float* out = (float*)d_out;

    char* ws = (char*)d_ws;
    size_t off = 0;
    auto alloc = [&](size_t bytes) -> char* {
        size_t o = off;
        off += (bytes + 255) & ~(size_t)255;
        return ws + o;
    };

    int* meta = (int*)alloc(64 * sizeof(int));
    int* tok_idx = (int*)alloc((size_t)TOK * 2 * sizeof(int));
    float* tok_prob = (float*)alloc((size_t)TOK * 2 * sizeof(float));
    int* list_tok = (int*)alloc((size_t)PAIRS * sizeof(int));
    float* list_prob = (float*)alloc((size_t)PAIRS * sizeof(float));
    unsigned short* xb = (unsigned short*)alloc((size_t)TOK * Dd * sizeof(unsigned short));
    unsigned short* hidden = (unsigned short*)alloc((size_t)PAIRS * Ff * sizeof(unsigned short));
    unsigned short* h1raw = (unsigned short*)alloc((size_t)PAIRS * Ff * sizeof(unsigned short));  // fallback path only

    // bf16 weight copies
    size_t wbytes = (size_t)Ee * Ff * Dd * sizeof(unsigned short);
    bool has_w = (ws_size >= off + 3 * wbytes + 4096);
    unsigned short *W1b = nullptr, *W2b = nullptr, *W3b = nullptr;
    if (has_w) {
        W1b = (unsigned short*)alloc(wbytes);
        W2b = (unsigned short*)alloc(wbytes);
        W3b = (unsigned short*)alloc(wbytes);
    }

    // out pre-zeroed for the atomic-accumulate epilogue
    zero_kernel<<<dim3(TOK * Dd / 4 / 256), dim3(256), 0, stream>>>(out, TOK * Dd / 4);

    gating_kernel<<<dim3(TOK / 4), dim3(256), 0, stream>>>(x, Wg, tok_idx, tok_prob);
    route_kernel<<<dim3(1), dim3(1024), 0, stream>>>(tok_idx, tok_prob, meta,
                                                     list_tok, list_prob);

    int xn4 = TOK * Dd / 4;
    cvt_kernel<<<dim3((xn4 + 255) / 256), dim3(256), 0, stream>>>(x, xb, xn4);

    if (has_w) {
        dim3 blk(256);
        int wn4 = Ee * Ff * Dd / 4;
        cvt_kernel<<<dim3((wn4 + 255) / 256), blk, 0, stream>>>(W1, W1b, wn4);
        cvt_kernel<<<dim3((wn4 + 255) / 256), blk, 0, stream>>>(W2, W2b, wn4);
        cvt_kernel<<<dim3((wn4 + 255) / 256), blk, 0, stream>>>(W3, W3b, wn4);
        // fused gemm1 (grid = 8 e x 16 nblk x 32 mblk, locality-swizzled 1D)
        rgemm12_kernel<<<dim3(8 * 16 * 32), blk, 0, stream>>>(
            xb, W1b, W2b, hidden, list_tok, meta);
        // gemm2 + combine (grid = 8 e x 32 mblk x 8 nblk, locality-swizzled 1D)
        rg2_kernel<<<dim3(8 * 32 * 8), blk, 0, stream>>>(
            hidden, W3b, out, list_tok, list_prob, meta);
    } else {
        dim3 g1(Ff / 128, 32, Ee), g2(Dd / 128, 32, Ee), blk(256);
        rgemm_kernel<0><<<g1, blk, 0, stream>>>(
            xb, W1, h1raw, nullptr, nullptr, list_tok, list_prob, meta, Dd, Ff, 1);
        rgemm_kernel<1><<<g1, blk, 0, stream>>>(
            xb, W2, h1raw, hidden, nullptr, list_tok, list_prob, meta, Dd, Ff, 1);
        rgemm_kernel<2><<<g2, blk, 0, stream>>>(
            hidden, W3, nullptr, nullptr, out, list_tok, list_prob, meta, Ff, Dd, 0);
    }
}

// Round 6
// 443.552 us; speedup vs baseline: 1.1112x; 1.0108x over previous
//
#include <hip/hip_runtime.h>
#include <hip/hip_bf16.h>
#include <cstdint>

// MoE feed-forward, routed top-2 of 8 experts.
// B=2 S=2048 D=1024 F=2048 E=8 K=2.
// R11: persistent blocks. R10 post-mortem: expert-pinning swizzle was the
//   poison (R9+R10 both regressed, HBM BW dropped) -> reverted to R8 order.
//   Re-derived arithmetic: with cnt~1024/expert, 3/4 of the 4096-block grid
//   exits at m0>=cnt -> ~1024 active blocks over 768 residency slots = 1.33
//   "shifts" (one full, one 1/3-full) + dead-block churn = measured 16.6%
//   occupancy; nothing saturated (LDS reads ~21 B/cyc of 85 ceiling, Mfma 25%).
//   Latency/occupancy-bound -> persistent grid (768 / 512 blocks) enumerating
//   EXACTLY the active tiles from meta in R8's order (A-tile-sharing kept).
//   setprio removed (null here; m190: can hurt lockstep GEMM).
//   (kept: R8 inner loop byte-for-byte - counted vmcnt 2-deep, XOR chunk
//    swizzle -> 0 bank conflicts, dual-acc fused gemm1, atomic combine)

#define Dd 1024
#define Ff 2048
#define Ee 8
#define TOK 4096
#define PAIRS 8192

typedef __attribute__((ext_vector_type(8))) short short8;
typedef __attribute__((ext_vector_type(4))) float floatx4;

__device__ __forceinline__ unsigned short f2bf(float f) {
    unsigned int u = __float_as_uint(f);
    unsigned int r = (u + 0x7FFFu + ((u >> 16) & 1u)) >> 16;
    return (unsigned short)r;
}
__device__ __forceinline__ float bf2f(unsigned short u) {
    return __uint_as_float(((unsigned)u) << 16);
}

// async 16B/lane global->LDS. lds ptr is wave-uniform; lane i lands at lds + i*16B.
__device__ __forceinline__ void gload16(const unsigned short* g, unsigned short* l) {
    __builtin_amdgcn_global_load_lds(
        (const __attribute__((address_space(1))) unsigned int*)g,
        (__attribute__((address_space(3))) unsigned int*)l,
        16, 0, 0);
}

// ---------------- zero out ----------------
__global__ void zero_kernel(float* __restrict__ out, int n4) {
    int i = blockIdx.x * blockDim.x + threadIdx.x;
    if (i < n4) reinterpret_cast<float4*>(out)[i] = make_float4(0.f, 0.f, 0.f, 0.f);
}

// ---------------- gating: fp32 scores, top-2, softmax (NO atomics) ----------------
__global__ void gating_kernel(const float* __restrict__ x, const float* __restrict__ Wg,
                              int* __restrict__ tok_idx, float* __restrict__ tok_prob) {
    int lane = threadIdx.x & 63;
    int w = threadIdx.x >> 6;
    int t = blockIdx.x * 4 + w;

    float xr[16];
    const float* xp = x + (size_t)t * Dd;
#pragma unroll
    for (int i = 0; i < 16; i++) xr[i] = xp[lane + i * 64];

    float sc[Ee];
    for (int e = 0; e < Ee; e++) {
        const float* wp = Wg + (size_t)e * Dd;
        float p = 0.f;
#pragma unroll
        for (int i = 0; i < 16; i++) p += xr[i] * wp[lane + i * 64];
        for (int off = 32; off > 0; off >>= 1) p += __shfl_xor(p, off);
        sc[e] = p;
    }
    if (lane == 0) {
        int e1 = 0, e2 = 0;
        float b1 = -1e30f, b2 = -1e30f;
        for (int e = 0; e < Ee; e++) {
            float s = sc[e];
            if (s > b1) { b2 = b1; e2 = e1; b1 = s; e1 = e; }
            else if (s > b2) { b2 = s; e2 = e; }
        }
        float p1 = 1.f / (1.f + expf(b2 - b1));
        float p2 = 1.f - p1;
        tok_idx[t * 2 + 0] = e1;
        tok_idx[t * 2 + 1] = e2;
        tok_prob[t * 2 + 0] = p1;
        tok_prob[t * 2 + 1] = p2;
    }
}

// ---------------- route: fused count + scan + stable scatter, one block ----------------
__global__ __launch_bounds__(1024) void route_kernel(
    const int* __restrict__ tok_idx, const float* __restrict__ tok_prob,
    int* __restrict__ meta, int* __restrict__ list_tok,
    float* __restrict__ list_prob) {
    int tid = threadIdx.x;
    int lane = tid & 63, w = tid >> 6;   // 16 waves

    int e_loc[8];
#pragma unroll
    for (int j = 0; j < 8; j++) e_loc[j] = tok_idx[tid * 8 + j];

    int h[Ee];
#pragma unroll
    for (int e = 0; e < Ee; e++) {
        int c = 0;
#pragma unroll
        for (int j = 0; j < 8; j++) c += (e_loc[j] == e) ? 1 : 0;
        h[e] = c;
    }

    int pre[Ee], tot[Ee];
#pragma unroll
    for (int e = 0; e < Ee; e++) {
        int v = h[e];
        for (int d = 1; d < 64; d <<= 1) {
            int u = __shfl_up(v, d, 64);
            if (lane >= d) v += u;
        }
        pre[e] = v - h[e];
        tot[e] = __shfl(v, 63, 64);
    }

    __shared__ int wtot[16][Ee];
    __shared__ int wbase[16][Ee];
    __shared__ int ebase[Ee];
    if (lane == 0)
#pragma unroll
        for (int e = 0; e < Ee; e++) wtot[w][e] = tot[e];
    __syncthreads();
    if (tid == 0) {
        int etot[Ee];
        for (int e = 0; e < Ee; e++) {
            int s = 0;
            for (int ww = 0; ww < 16; ww++) { wbase[ww][e] = s; s += wtot[ww][e]; }
            etot[e] = s;
        }
        int b = 0;
        for (int e = 0; e < Ee; e++) {
            ebase[e] = b;
            meta[e] = etot[e];       // counts
            meta[16 + e] = b;        // bases
            b += etot[e];
        }
    }
    __syncthreads();

    int off[Ee];
#pragma unroll
    for (int e = 0; e < Ee; e++) off[e] = ebase[e] + wbase[w][e] + pre[e];

#pragma unroll
    for (int j = 0; j < 8; j++) {
        int item = tid * 8 + j;
        int el = e_loc[j];
        int pos = 0;
#pragma unroll
        for (int e = 0; e < Ee; e++) {
            if (el == e) { pos = off[e]; off[e] = pos + 1; }
        }
        list_tok[pos] = item >> 1;
        list_prob[pos] = tok_prob[item];
    }
}

// ---------------- fp32 -> bf16 convert ----------------
__global__ void cvt_kernel(const float* __restrict__ src, unsigned short* __restrict__ dst, int n4) {
    int i = blockIdx.x * blockDim.x + threadIdx.x;
    if (i >= n4) return;
    float4 v = reinterpret_cast<const float4*>(src)[i];
    uint2 o;
    o.x = (unsigned)f2bf(v.x) | ((unsigned)f2bf(v.y) << 16);
    o.y = (unsigned)f2bf(v.z) | ((unsigned)f2bf(v.w) << 16);
    reinterpret_cast<uint2*>(dst)[i] = o;
}

// ---------------- manual fp32->bf16 LDS staging (fallback path only, linear) ----------------
__device__ __forceinline__ void stage16(unsigned short* dst, const float* src) {
    const float4* s = reinterpret_cast<const float4*>(src);
    float4 v0 = s[0], v1 = s[1], v2 = s[2], v3 = s[3];
    uint4 o0, o1;
    o0.x = (unsigned)f2bf(v0.x) | ((unsigned)f2bf(v0.y) << 16);
    o0.y = (unsigned)f2bf(v0.z) | ((unsigned)f2bf(v0.w) << 16);
    o0.z = (unsigned)f2bf(v1.x) | ((unsigned)f2bf(v1.y) << 16);
    o0.w = (unsigned)f2bf(v1.z) | ((unsigned)f2bf(v1.w) << 16);
    o1.x = (unsigned)f2bf(v2.x) | ((unsigned)f2bf(v2.y) << 16);
    o1.y = (unsigned)f2bf(v2.z) | ((unsigned)f2bf(v2.w) << 16);
    o1.z = (unsigned)f2bf(v3.x) | ((unsigned)f2bf(v3.y) << 16);
    o1.w = (unsigned)f2bf(v3.z) | ((unsigned)f2bf(v3.w) << 16);
    uint4* d = reinterpret_cast<uint4*>(dst);
    d[0] = o0;
    d[1] = o1;
}

// ============ fused gemm1 (persistent): hidden = silu(x W1^T) * (x W2^T) ============
// R8 inner loop: 128x128 tile, BK=32, 4 waves (2Mx2N, 64x64/wave), dual acc,
// counted-vmcnt 2-deep (vmcnt(6)), XOR chunk swizzle both sides.
// Persistent wrapper: 768 blocks grid-stride over the ACTIVE tiles only,
// enumerated from meta in R8's order (e-major, mblk, nblk fastest).
__global__ __launch_bounds__(256, 2) void rgemm12_kernel(
    const unsigned short* __restrict__ A,      // xb
    const unsigned short* __restrict__ B1w,    // W1b
    const unsigned short* __restrict__ B2w,    // W2b
    unsigned short* __restrict__ hout,         // hidden (bf16)
    const int* __restrict__ list_tok, const int* __restrict__ meta) {
    __shared__ unsigned short sA[2 * 128 * 32];
    __shared__ unsigned short sB1[2 * 128 * 32];
    __shared__ unsigned short sB2[2 * 128 * 32];

    int tid = threadIdx.x;
    int lane = tid & 63, w = tid >> 6;
    int wm = w >> 1, wn = w & 1;
    int lane15 = lane & 15, quad = lane >> 4;

    // item-independent staging geometry
    int jr = w * 32 + (lane >> 2);
    int c8 = (((lane & 3) ^ ((lane >> 3) & 3)) * 8);
    unsigned short* ldsA0  = sA  + w * 1024;
    unsigned short* ldsA1  = ldsA0 + 512;
    unsigned short* ldsB10 = sB1 + w * 1024;
    unsigned short* ldsB11 = ldsB10 + 512;
    unsigned short* ldsB20 = sB2 + w * 1024;
    unsigned short* ldsB21 = ldsB20 + 512;

    int rsw = (lane15 >> 1) & 3;
    const unsigned short* sAr  = &sA [(wm * 64 + lane15) * 32 + (quad ^ rsw) * 8];
    const unsigned short* sB1r = &sB1[(wn * 64 + lane15) * 32 + (quad ^ rsw) * 8];
    const unsigned short* sB2r = &sB2[(wn * 64 + lane15) * 32 + (quad ^ rsw) * 8];

    // active-tile enumeration from meta
    int cntv[Ee], basv[Ee], itemsv[Ee];
    int total = 0;
#pragma unroll
    for (int ee = 0; ee < Ee; ee++) {
        cntv[ee] = meta[ee];
        basv[ee] = meta[16 + ee];
        itemsv[ee] = ((cntv[ee] + 127) >> 7) * 16;   // mblks * 16 nblks
        total += itemsv[ee];
    }

    for (int item = blockIdx.x; item < total; item += gridDim.x) {
        int rem = item, e = 0, done = 0;
#pragma unroll
        for (int ee = 0; ee < Ee - 1; ee++) {
            if (!done) {
                if (rem >= itemsv[ee]) { rem -= itemsv[ee]; e = ee + 1; }
                else done = 1;
            }
        }
        int mblk = rem >> 4, nblk = rem & 15;
        int cnt = cntv[e], bs = basv[e];
        int m0 = mblk * 128, n0 = nblk * 128;

        int r0 = m0 + jr;      if (r0 >= cnt) r0 = cnt - 1;
        int r1 = m0 + jr + 16; if (r1 >= cnt) r1 = cnt - 1;
        size_t ar0 = (size_t)list_tok[bs + r0];
        size_t ar1 = (size_t)list_tok[bs + r1];
        const unsigned short* a0 = A + ar0 * Dd + c8;
        const unsigned short* a1 = A + ar1 * Dd + c8;
        const unsigned short* b10 = B1w + ((size_t)e * Ff + n0 + jr) * Dd + c8;
        const unsigned short* b11 = b10 + (size_t)16 * Dd;
        const unsigned short* b20 = B2w + ((size_t)e * Ff + n0 + jr) * Dd + c8;
        const unsigned short* b21 = b20 + (size_t)16 * Dd;

        floatx4 acc1[4][4] = {};
        floatx4 acc2[4][4] = {};

        // prologue: stage tiles 0 and 1 (12 loads in flight)
#pragma unroll
        for (int t = 0; t < 2; t++) {
            int k = t * 32, o = t * 4096;
            gload16(a0 + k,  ldsA0  + o);
            gload16(a1 + k,  ldsA1  + o);
            gload16(b10 + k, ldsB10 + o);
            gload16(b11 + k, ldsB11 + o);
            gload16(b20 + k, ldsB20 + o);
            gload16(b21 + k, ldsB21 + o);
        }

        int cur = 0;
        for (int t = 0; t < 32; ++t) {
            if (t < 31) asm volatile("s_waitcnt vmcnt(6)" ::: "memory");
            else        asm volatile("s_waitcnt vmcnt(0)" ::: "memory");
            __builtin_amdgcn_s_barrier();
            asm volatile("" ::: "memory");

            int o = cur * 4096;
            short8 af[4], b1f[4], b2f[4];
#pragma unroll
            for (int i = 0; i < 4; i++) {
                af[i]  = *reinterpret_cast<const short8*>(sAr  + o + i * 16 * 32);
                b1f[i] = *reinterpret_cast<const short8*>(sB1r + o + i * 16 * 32);
                b2f[i] = *reinterpret_cast<const short8*>(sB2r + o + i * 16 * 32);
            }
#pragma unroll
            for (int mi = 0; mi < 4; mi++)
#pragma unroll
                for (int ni = 0; ni < 4; ni++) {
                    acc1[mi][ni] = __builtin_amdgcn_mfma_f32_16x16x32_bf16(af[mi], b1f[ni], acc1[mi][ni], 0, 0, 0);
                    acc2[mi][ni] = __builtin_amdgcn_mfma_f32_16x16x32_bf16(af[mi], b2f[ni], acc2[mi][ni], 0, 0, 0);
                }
            asm volatile("" ::: "memory");
            __builtin_amdgcn_s_barrier();   // all waves done reading buf[cur]
            asm volatile("" ::: "memory");
            if (t + 2 < 32) {               // restage buf[cur] with tile t+2
                int k = (t + 2) * 32;
                gload16(a0 + k,  ldsA0  + o);
                gload16(a1 + k,  ldsA1  + o);
                gload16(b10 + k, ldsB10 + o);
                gload16(b11 + k, ldsB11 + o);
                gload16(b20 + k, ldsB20 + o);
                gload16(b21 + k, ldsB21 + o);
            }
            cur ^= 1;
        }

        // epilogue: hidden = silu(h1) * h2 on fp32 acc
#pragma unroll
        for (int mi = 0; mi < 4; mi++) {
#pragma unroll
            for (int i = 0; i < 4; i++) {
                int rr = m0 + wm * 64 + mi * 16 + quad * 4 + i;
                if (rr < cnt) {
                    int pos = bs + rr;
                    unsigned short* hp = hout + (size_t)pos * Ff + n0 + wn * 64;
#pragma unroll
                    for (int ni = 0; ni < 4; ni++) {
                        float h1 = acc1[mi][ni][i];
                        float h2 = acc2[mi][ni][i];
                        float hv = h1 / (1.f + expf(-h1)) * h2;
                        hp[ni * 16 + lane15] = f2bf(hv);
                    }
                }
            }
        }
        // final K-iteration ended with a barrier after all reads -> next item's
        // staging into LDS is safe without an extra __syncthreads.
    }
}

// ============ gemm2 + combine (persistent): out[tok] += prob * (hidden W3^T) ============
// R8 inner loop: 128x128 tile, 4 waves, single acc, vmcnt(4) 2-deep.
// Persistent wrapper: 512 blocks over active tiles (e-major, mblk, nblk fastest).
__global__ __launch_bounds__(256, 2) void rg2_kernel(
    const unsigned short* __restrict__ A,      // hidden
    const unsigned short* __restrict__ B3,     // W3b (e, d, f)
    float* __restrict__ out,                   // token-indexed atomic output
    const int* __restrict__ list_tok, const float* __restrict__ list_prob,
    const int* __restrict__ meta) {
    __shared__ unsigned short sA[2 * 128 * 32];
    __shared__ unsigned short sB[2 * 128 * 32];

    int tid = threadIdx.x;
    int lane = tid & 63, w = tid >> 6;
    int wm = w >> 1, wn = w & 1;
    int lane15 = lane & 15, quad = lane >> 4;

    int jr = w * 32 + (lane >> 2);
    int c8 = (((lane & 3) ^ ((lane >> 3) & 3)) * 8);
    unsigned short* ldsA0 = sA + w * 1024;
    unsigned short* ldsA1 = ldsA0 + 512;
    unsigned short* ldsB0 = sB + w * 1024;
    unsigned short* ldsB1 = ldsB0 + 512;

    int rsw = (lane15 >> 1) & 3;
    const unsigned short* sAr = &sA[(wm * 64 + lane15) * 32 + (quad ^ rsw) * 8];
    const unsigned short* sBr = &sB[(wn * 64 + lane15) * 32 + (quad ^ rsw) * 8];

    int cntv[Ee], basv[Ee], itemsv[Ee];
    int total = 0;
#pragma unroll
    for (int ee = 0; ee < Ee; ee++) {
        cntv[ee] = meta[ee];
        basv[ee] = meta[16 + ee];
        itemsv[ee] = ((cntv[ee] + 127) >> 7) * 8;    // mblks * 8 nblks
        total += itemsv[ee];
    }

    for (int item = blockIdx.x; item < total; item += gridDim.x) {
        int rem = item, e = 0, done = 0;
#pragma unroll
        for (int ee = 0; ee < Ee - 1; ee++) {
            if (!done) {
                if (rem >= itemsv[ee]) { rem -= itemsv[ee]; e = ee + 1; }
                else done = 1;
            }
        }
        int mblk = rem >> 3, nblk = rem & 7;
        int cnt = cntv[e], bs = basv[e];
        int m0 = mblk * 128, n0 = nblk * 128;

        int r0 = m0 + jr;      if (r0 >= cnt) r0 = cnt - 1;
        int r1 = m0 + jr + 16; if (r1 >= cnt) r1 = cnt - 1;
        const unsigned short* a0 = A + (size_t)(bs + r0) * Ff + c8;   // rows contiguous
        const unsigned short* a1 = A + (size_t)(bs + r1) * Ff + c8;
        const unsigned short* b0 = B3 + ((size_t)e * Dd + n0 + jr) * Ff + c8;
        const unsigned short* b1 = b0 + (size_t)16 * Ff;

        floatx4 acc[4][4] = {};

        // prologue: stage tiles 0 and 1 (8 loads in flight)
#pragma unroll
        for (int t = 0; t < 2; t++) {
            int k = t * 32, o = t * 4096;
            gload16(a0 + k, ldsA0 + o);
            gload16(a1 + k, ldsA1 + o);
            gload16(b0 + k, ldsB0 + o);
            gload16(b1 + k, ldsB1 + o);
        }
        int cur = 0;
        const int NT = Ff / 32;   // 64
        for (int t = 0; t < NT; ++t) {
            if (t + 1 < NT) asm volatile("s_waitcnt vmcnt(4)" ::: "memory");
            else            asm volatile("s_waitcnt vmcnt(0)" ::: "memory");
            __builtin_amdgcn_s_barrier();
            asm volatile("" ::: "memory");

            int o = cur * 4096;
            short8 af[4], bfr[4];
#pragma unroll
            for (int i = 0; i < 4; i++) {
                af[i]  = *reinterpret_cast<const short8*>(sAr + o + i * 16 * 32);
                bfr[i] = *reinterpret_cast<const short8*>(sBr + o + i * 16 * 32);
            }
#pragma unroll
            for (int mi = 0; mi < 4; mi++)
#pragma unroll
                for (int ni = 0; ni < 4; ni++)
                    acc[mi][ni] = __builtin_amdgcn_mfma_f32_16x16x32_bf16(af[mi], bfr[ni], acc[mi][ni], 0, 0, 0);
            asm volatile("" ::: "memory");
            __builtin_amdgcn_s_barrier();
            asm volatile("" ::: "memory");
            if (t + 2 < NT) {
                int k = (t + 2) * 32;
                gload16(a0 + k, ldsA0 + o);
                gload16(a1 + k, ldsA1 + o);
                gload16(b0 + k, ldsB0 + o);
                gload16(b1 + k, ldsB1 + o);
            }
            cur ^= 1;
        }

        // epilogue: fused combine (exactly 2 contributions per out element)
#pragma unroll
        for (int mi = 0; mi < 4; mi++) {
#pragma unroll
            for (int i = 0; i < 4; i++) {
                int rr = m0 + wm * 64 + mi * 16 + quad * 4 + i;
                if (rr < cnt) {
                    int pos = bs + rr;
                    int tok = list_tok[pos];
                    float p = list_prob[pos];
                    float* yp = out + (size_t)tok * Dd + n0 + wn * 64;
#pragma unroll
                    for (int ni = 0; ni < 4; ni++)
                        atomicAdd(&yp[ni * 16 + lane15], p * acc[mi][ni][i]);
                }
            }
        }
    }
}

// ============ fallback routed GEMM (fp32 weights, correctness-first) ============
template <int EPI>
__global__ __launch_bounds__(256) void rgemm_kernel(
    const unsigned short* __restrict__ A,
    const float* __restrict__ Bw,
    unsigned short* __restrict__ h1raw,
    unsigned short* __restrict__ hout,
    float* __restrict__ out,
    const int* __restrict__ list_tok, const float* __restrict__ list_prob,
    const int* __restrict__ meta,
    int AK, int BN, int arow_is_list) {
    int e = blockIdx.z;
    int cnt = meta[e];
    int m0 = blockIdx.y * 128;
    if (m0 >= cnt) return;
    int bs = meta[16 + e];
    int n0 = blockIdx.x * 128;

    __shared__ unsigned short sA[2 * 128 * 32];
    __shared__ unsigned short sB[2 * 128 * 32];

    int tid = threadIdx.x;
    int lane = tid & 63, w = tid >> 6;
    int wm = w >> 1, wn = w & 1;
    int lane15 = lane & 15, quad = lane >> 4;

    int jr = w * 32 + (lane >> 2);
    int c8 = (lane & 3) * 8;
    unsigned short* ldsA0 = sA + w * 1024;
    unsigned short* ldsA1 = ldsA0 + 512;

    int r0 = m0 + jr;      if (r0 >= cnt) r0 = cnt - 1;
    int r1 = m0 + jr + 16; if (r1 >= cnt) r1 = cnt - 1;
    size_t ar0 = arow_is_list ? (size_t)list_tok[bs + r0] : (size_t)(bs + r0);
    size_t ar1 = arow_is_list ? (size_t)list_tok[bs + r1] : (size_t)(bs + r1);
    const unsigned short* a0 = A + ar0 * AK + c8;
    const unsigned short* a1 = A + ar1 * AK + c8;

    int row = tid >> 1, colb = (tid & 1) * 16;
    const float* bmp = Bw + ((size_t)e * BN + n0 + row) * AK + colb;
    unsigned short* sBw = &sB[row * 32 + colb];

    const unsigned short* sAr = &sA[(wm * 64 + lane15) * 32 + quad * 8];
    const unsigned short* sBr = &sB[(wn * 64 + lane15) * 32 + quad * 8];

    floatx4 acc[4][4] = {};

    gload16(a0, ldsA0);
    gload16(a1, ldsA1);
    stage16(sBw, bmp);
    __syncthreads();
    int cur = 0;
    for (int k0 = 0; k0 < AK; k0 += 32) {
        if (k0 + 32 < AK) {
            int o = (cur ^ 1) * 4096;
            int k = k0 + 32;
            gload16(a0 + k, ldsA0 + o);
            gload16(a1 + k, ldsA1 + o);
            stage16(sBw + o, bmp + k);
        }
        int o = cur * 4096;
        short8 af[4], bfr[4];
#pragma unroll
        for (int i = 0; i < 4; i++) {
            af[i]  = *reinterpret_cast<const short8*>(sAr + o + i * 16 * 32);
            bfr[i] = *reinterpret_cast<const short8*>(sBr + o + i * 16 * 32);
        }
#pragma unroll
        for (int mi = 0; mi < 4; mi++)
#pragma unroll
            for (int ni = 0; ni < 4; ni++)
                acc[mi][ni] = __builtin_amdgcn_mfma_f32_16x16x32_bf16(af[mi], bfr[ni], acc[mi][ni], 0, 0, 0);
        __syncthreads();
        cur ^= 1;
    }

#pragma unroll
    for (int mi = 0; mi < 4; mi++) {
#pragma unroll
        for (int i = 0; i < 4; i++) {
            int rr = m0 + wm * 64 + mi * 16 + quad * 4 + i;
            if (rr < cnt) {
                int pos = bs + rr;
                if constexpr (EPI == 0) {
                    unsigned short* hp = h1raw + (size_t)pos * BN + n0 + wn * 64;
#pragma unroll
                    for (int ni = 0; ni < 4; ni++)
                        hp[ni * 16 + lane15] = f2bf(acc[mi][ni][i]);
                } else if constexpr (EPI == 1) {
                    const unsigned short* h1p = h1raw + (size_t)pos * BN + n0 + wn * 64;
                    unsigned short* hp = hout + (size_t)pos * BN + n0 + wn * 64;
#pragma unroll
                    for (int ni = 0; ni < 4; ni++) {
                        float h1 = bf2f(h1p[ni * 16 + lane15]);
                        float h2 = acc[mi][ni][i];
                        float hv = h1 / (1.f + expf(-h1)) * h2;
                        hp[ni * 16 + lane15] = f2bf(hv);
                    }
                } else {
                    int tok = list_tok[pos];
                    float p = list_prob[pos];
                    float* yp = out + (size_t)tok * BN + n0 + wn * 64;
#pragma unroll
                    for (int ni = 0; ni < 4; ni++)
                        atomicAdd(&yp[ni * 16 + lane15], p * acc[mi][ni][i]);
                }
            }
        }
    }
}

// ---------------- host launch ----------------
extern "C" void kernel_launch(void* const* d_in, const int* in_sizes, int n_in,
                              void* d_out, int out_size, void* d_ws, size_t ws_size,
                              hipStream_t stream) {
    const float* x  = (const float*)d_in[0];
    const float* Wg = (const float*)d_in[1];
    const float* W1 = (const float*)d_in[2];
    const float* W2 = (const float*)d_in[3];
    const float* W3 = (const float*)d_in[4];
    float* out = (float*)d_out;

    char* ws = (char*)d_ws;
    size_t off = 0;
    auto alloc = [&](size_t bytes) -> char* {
        size_t o = off;
        off += (bytes + 255) & ~(size_t)255;
        return ws + o;
    };

    int* meta = (int*)alloc(64 * sizeof(int));
    int* tok_idx = (int*)alloc((size_t)TOK * 2 * sizeof(int));
    float* tok_prob = (float*)alloc((size_t)TOK * 2 * sizeof(float));
    int* list_tok = (int*)alloc((size_t)PAIRS * sizeof(int));
    float* list_prob = (float*)alloc((size_t)PAIRS * sizeof(float));
    unsigned short* xb = (unsigned short*)alloc((size_t)TOK * Dd * sizeof(unsigned short));
    unsigned short* hidden = (unsigned short*)alloc((size_t)PAIRS * Ff * sizeof(unsigned short));
    unsigned short* h1raw = (unsigned short*)alloc((size_t)PAIRS * Ff * sizeof(unsigned short));  // fallback path only

    // bf16 weight copies
    size_t wbytes = (size_t)Ee * Ff * Dd * sizeof(unsigned short);
    bool has_w = (ws_size >= off + 3 * wbytes + 4096);
    unsigned short *W1b = nullptr, *W2b = nullptr, *W3b = nullptr;
    if (has_w) {
        W1b = (unsigned short*)alloc(wbytes);
        W2b = (unsigned short*)alloc(wbytes);
        W3b = (unsigned short*)alloc(wbytes);
    }

    // out pre-zeroed for the atomic-accumulate epilogue
    zero_kernel<<<dim3(TOK * Dd / 4 / 256), dim3(256), 0, stream>>>(out, TOK * Dd / 4);

    gating_kernel<<<dim3(TOK / 4), dim3(256), 0, stream>>>(x, Wg, tok_idx, tok_prob);
    route_kernel<<<dim3(1), dim3(1024), 0, stream>>>(tok_idx, tok_prob, meta,
                                                     list_tok, list_prob);

    int xn4 = TOK * Dd / 4;
    cvt_kernel<<<dim3((xn4 + 255) / 256), dim3(256), 0, stream>>>(x, xb, xn4);

    if (has_w) {
        dim3 blk(256);
        int wn4 = Ee * Ff * Dd / 4;
        cvt_kernel<<<dim3((wn4 + 255) / 256), blk, 0, stream>>>(W1, W1b, wn4);
        cvt_kernel<<<dim3((wn4 + 255) / 256), blk, 0, stream>>>(W2, W2b, wn4);
        cvt_kernel<<<dim3((wn4 + 255) / 256), blk, 0, stream>>>(W3, W3b, wn4);
        // fused gemm1: persistent 768 blocks (3/CU x 256 CUs), active tiles only
        rgemm12_kernel<<<dim3(768), blk, 0, stream>>>(
            xb, W1b, W2b, hidden, list_tok, meta);
        // gemm2 + combine: persistent 512 blocks
        rg2_kernel<<<dim3(512), blk, 0, stream>>>(
            hidden, W3b, out, list_tok, list_prob, meta);
    } else {
        dim3 g1(Ff / 128, 32, Ee), g2(Dd / 128, 32, Ee), blk(256);
        rgemm_kernel<0><<<g1, blk, 0, stream>>>(
            xb, W1, h1raw, nullptr, nullptr, list_tok, list_prob, meta, Dd, Ff, 1);
        rgemm_kernel<1><<<g1, blk, 0, stream>>>(
            xb, W2, h1raw, hidden, nullptr, list_tok, list_prob, meta, Dd, Ff, 1);
        rgemm_kernel<2><<<g2, blk, 0, stream>>>(
            hidden, W3, nullptr, nullptr, out, list_tok, list_prob, meta, Ff, Dd, 0);
    }
}